// Round 11
// baseline (195.273 us; speedup 1.0000x reference)
//
#include <hip/hip_runtime.h>
#include <hip/hip_bf16.h>

// Problem constants
#define B_   8
#define S_   1024
#define D_   768
#define H_   16
#define PD_  48
#define PDP  64        // padded per-head dim
#define M_   8192      // B*S
#define BH_  128       // B*H

// 1/sqrt(48) * log2(e)  -> folded into Q so softmax is a bare exp2
#define QSCALE 0.20823031f

typedef __attribute__((ext_vector_type(8))) short short8;
typedef __attribute__((ext_vector_type(4))) float floatx4;

__device__ __forceinline__ unsigned short f2bf(float f) {
    __hip_bfloat16 h = __float2bfloat16(f);
    return *reinterpret_cast<unsigned short*>(&h);
}

// async 16B global -> LDS (direct, no VGPR round trip). LDS dest must be
// wave-uniform base + lane*16; any swizzle must be folded into the GLOBAL addr.
__device__ __forceinline__ void async_copy16(const unsigned short* gptr, unsigned short* lptr) {
    __builtin_amdgcn_global_load_lds(
        (const __attribute__((address_space(1))) unsigned int*)gptr,
        (__attribute__((address_space(3))) unsigned int*)lptr, 16, 0, 0);
}

// ---------------------------------------- fused: convert X + transpose weights
// blocks [0,6144): cast X tile to bf16. blocks [6144,8448): W transpose+cast.
__global__ __launch_bounds__(256) void prep_kernel(
    const float* __restrict__ X, unsigned short* __restrict__ Xb,
    const float* __restrict__ w0, const float* __restrict__ w1,
    const float* __restrict__ w2, const float* __restrict__ w3,
    unsigned short* __restrict__ Wtall) {
    __shared__ float tile[32][33];
    const int tid = threadIdx.x;
    const int bx = blockIdx.x;
    if (bx < 6144) {
        long i = ((long)bx * 256 + tid) * 4;
        float4 v = *(const float4*)(X + i);
        ushort4 o;
        o.x = f2bf(v.x); o.y = f2bf(v.y); o.z = f2bf(v.z); o.w = f2bf(v.w);
        *(ushort4*)(Xb + i) = o;
        return;
    }
    const int t = bx - 6144;
    const int z = t / 576, r = t % 576;
    const int nt = (r % 24) * 32, kt = (r / 24) * 32;
    const int tx = tid & 31, ty = tid >> 5;
    const float* W = (z == 0) ? w0 : (z == 1) ? w1 : (z == 2) ? w2 : w3;
    unsigned short* Wt = Wtall + (long)z * D_ * D_;
#pragma unroll
    for (int i = 0; i < 4; i++)
        tile[ty + i * 8][tx] = W[(long)(kt + ty + i * 8) * D_ + nt + tx];
    __syncthreads();
#pragma unroll
    for (int i = 0; i < 4; i++)
        Wt[(long)(nt + ty + i * 8) * D_ + kt + tx] = f2bf(tile[tx][ty + i * 8]);
}

// ------------------------------------------------------- QKV projection GEMM
// BN=192 (4 heads exactly) — R10-verified win. Stall-bound at per-k-step
// barrier drains; wide B-tile buys 48 MFMA/wave per barrier pair; same MFMA
// issue per CU-interval but 1/3 fewer chip-wide drain events + A re-stages.
// Grid 64 x 4 x 3 = 768 blocks = exactly 3.0 blocks/CU.
// LDS = 16KB(A) + 24KB(B) = 40KB. __launch_bounds__(256,3) caps VGPR at 170.
// m-major grid x => per-XCD L2 pins 8 A-tiles; one B-tile streams at a time.
__global__ __launch_bounds__(256, 3) void gemm_qkv_kernel(
    const unsigned short* __restrict__ Xb, const unsigned short* __restrict__ Wtall,
    const float* __restrict__ bq, const float* __restrict__ bk,
    const float* __restrict__ bv, unsigned short* __restrict__ QKV) {
    __shared__ __align__(16) unsigned short Asm[128 * 64];
    __shared__ __align__(16) unsigned short Bsm[192 * 64];
    const int z = blockIdx.z;
    const int m0 = blockIdx.x * 128, n0 = blockIdx.y * 192;
    const float* bias = (z == 0) ? bq : (z == 1) ? bk : bv;
    const float vscale = (z == 0) ? QSCALE : 1.0f;
    const unsigned short* Ag  = Xb + (long)m0 * D_;
    const unsigned short* Btg = Wtall + (long)z * D_ * D_ + (long)n0 * D_;

    const int tid = threadIdx.x, lane = tid & 63, w = tid >> 6;
    const int wr = (w >> 1) * 64, wc = (w & 1) * 96;
    const int l15 = lane & 15, l4 = lane >> 4;
    const floatx4 zero = {0.f, 0.f, 0.f, 0.f};
    floatx4 acc[4][6];
#pragma unroll
    for (int mt = 0; mt < 4; mt++)
#pragma unroll
        for (int nt = 0; nt < 6; nt++) acc[mt][nt] = zero;

    for (int kb = 0; kb < D_; kb += 64) {
        // stage A[128x64]: 1024 16B chunks; B[192x64]: 1536 chunks.
#pragma unroll
        for (int i = 0; i < 4; i++) {
            int c = tid + i * 256;
            int row = c >> 3, seg = (c & 7) ^ (row & 7);
            async_copy16(&Ag[(long)row * D_ + kb + seg * 8], &Asm[c * 8]);
        }
#pragma unroll
        for (int i = 0; i < 6; i++) {
            int c = tid + i * 256;
            int row = c >> 3, seg = (c & 7) ^ (row & 7);
            async_copy16(&Btg[(long)row * D_ + kb + seg * 8], &Bsm[c * 8]);
        }
        __syncthreads();
#pragma unroll
        for (int kk = 0; kk < 2; kk++) {
            short8 af[4], bf[6];
#pragma unroll
            for (int mt = 0; mt < 4; mt++) {
                int r = wr + mt * 16 + l15;
                af[mt] = *(const short8*)&Asm[r * 64 + (((kk * 4 + l4) ^ (r & 7)) * 8)];
            }
#pragma unroll
            for (int nt = 0; nt < 6; nt++) {
                int c = wc + nt * 16 + l15;
                bf[nt] = *(const short8*)&Bsm[c * 64 + (((kk * 4 + l4) ^ (c & 7)) * 8)];
            }
#pragma unroll
            for (int mt = 0; mt < 4; mt++)
#pragma unroll
                for (int nt = 0; nt < 6; nt++)
                    acc[mt][nt] = __builtin_amdgcn_mfma_f32_16x16x32_bf16(
                        af[mt], bf[nt], acc[mt][nt], 0, 0, 0);
        }
        __syncthreads();
    }

    unsigned short* out = QKV + (long)z * BH_ * S_ * PDP;
#pragma unroll
    for (int nt = 0; nt < 6; nt++) {
        int n = n0 + wc + nt * 16 + l15;
        int h = n / PD_, pd = n % PD_;
        float bb = bias[n];
#pragma unroll
        for (int mt = 0; mt < 4; mt++) {
#pragma unroll
            for (int r = 0; r < 4; r++) {
                int m = m0 + wr + mt * 16 + l4 * 4 + r;
                int b = m >> 10, s = m & 1023;
                out[((long)(b * H_ + h) * S_ + s) * PDP + pd] = f2bf((acc[mt][nt][r] + bb) * vscale);
            }
        }
    }
}

// --------------------------------------------- V transpose: [bh,s,64]->[bh,64,s]
// Also writes the l-accumulator ones-column at d=48 and zeros at d=49..63.
__global__ __launch_bounds__(256) void transpose_v_kernel(
    const unsigned short* __restrict__ V, unsigned short* __restrict__ Vt) {
    __shared__ __align__(16) unsigned short T[64 * 64];  // [s][d] swizzled
    const int tid = threadIdx.x;
    const int st = blockIdx.x * 64, bh = blockIdx.y;
    const unsigned short* src = V + (long)bh * S_ * PDP;
    unsigned short* dst = Vt + (long)bh * PDP * S_;
#pragma unroll
    for (int i = 0; i < 2; i++) {
        int c = tid + i * 256;
        int row = c >> 3, seg = (c & 7) ^ (row & 7);
        async_copy16(&src[(long)(st + row) * PDP + seg * 8], &T[c * 8]);
    }
    __syncthreads();
    const int d = tid >> 2;
    unsigned short tmp[16];
#pragma unroll
    for (int j = 0; j < 16; j++) {
        int sl = (tid & 3) * 16 + j;
        unsigned short v = T[sl * 64 + ((d >> 3) ^ (sl & 7)) * 8 + (d & 7)];
        tmp[j] = (d < PD_) ? v : ((d == PD_) ? (unsigned short)0x3F80 : (unsigned short)0);
    }
    *(uint4*)&dst[(long)d * S_ + st + (tid & 3) * 16] = *(uint4*)&tmp[0];
    *(uint4*)&dst[(long)d * S_ + st + (tid & 3) * 16 + 8] = *(uint4*)&tmp[8];
}

// --------------------------------------------------------- output projection
// v3: BK=128. Same residency (LDS 32+16=48KB -> 3 blocks/CU capacity, grid
// 64x12=768=3.0/CU) but barrier events halve (6 k-steps, was 12) and MFMA per
// barrier interval doubles (32/wave, was 16) — residency-preserving variant of
// the R10-proven qkv amortization (m132's BK=128 fail was the 64KB/2-block
// case, avoided here). Swizzle: 16 segs/row, seg=(c&15)^(row&7); read side
// ((kk*4+l4)^(r&7))*8 — rows r,r+8 share a slot: 2-way, free.
// K accumulation order unchanged (same ordered K=32 chunk list) -> identical
// numerics.
__global__ __launch_bounds__(256) void gemm_out_kernel(
    const unsigned short* __restrict__ Ctx, const unsigned short* __restrict__ Wot,
    const float* __restrict__ bo, float* __restrict__ Out) {
    __shared__ __align__(16) unsigned short Asm[128 * 128];
    __shared__ __align__(16) unsigned short Bsm[64 * 128];
    const int tid = threadIdx.x, lane = tid & 63, w = tid >> 6;
    const int wr = w * 32;
    const int l15 = lane & 15, l4 = lane >> 4;
    const int m0 = blockIdx.x * 128, n0 = blockIdx.y * 64;
    const unsigned short* Ag = Ctx + (long)m0 * D_;
    const unsigned short* Btg = Wot + (long)n0 * D_;

    const floatx4 zero = {0.f, 0.f, 0.f, 0.f};
    floatx4 acc[2][4];
#pragma unroll
    for (int mt = 0; mt < 2; mt++)
#pragma unroll
        for (int nt = 0; nt < 4; nt++) acc[mt][nt] = zero;

    for (int kb = 0; kb < D_; kb += 128) {
        // stage A[128x128]: 2048 16B chunks; B[64x128]: 1024 chunks.
#pragma unroll
        for (int i = 0; i < 8; i++) {
            int c = tid + i * 256;
            int row = c >> 4, seg = (c & 15) ^ (row & 7);
            async_copy16(&Ag[(long)row * D_ + kb + seg * 8], &Asm[c * 8]);
        }
#pragma unroll
        for (int i = 0; i < 4; i++) {
            int c = tid + i * 256;
            int row = c >> 4, seg = (c & 15) ^ (row & 7);
            async_copy16(&Btg[(long)row * D_ + kb + seg * 8], &Bsm[c * 8]);
        }
        __syncthreads();
#pragma unroll
        for (int kk = 0; kk < 4; kk++) {
            short8 af[2], bf[4];
#pragma unroll
            for (int mt = 0; mt < 2; mt++) {
                int r = wr + mt * 16 + l15;
                af[mt] = *(const short8*)&Asm[r * 128 + (((kk * 4 + l4) ^ (r & 7)) * 8)];
            }
#pragma unroll
            for (int nt = 0; nt < 4; nt++) {
                int c = nt * 16 + l15;
                bf[nt] = *(const short8*)&Bsm[c * 128 + (((kk * 4 + l4) ^ (c & 7)) * 8)];
            }
#pragma unroll
            for (int mt = 0; mt < 2; mt++)
#pragma unroll
                for (int nt = 0; nt < 4; nt++)
                    acc[mt][nt] = __builtin_amdgcn_mfma_f32_16x16x32_bf16(
                        af[mt], bf[nt], acc[mt][nt], 0, 0, 0);
        }
        __syncthreads();
    }

#pragma unroll
    for (int nt = 0; nt < 4; nt++) {
        int n = n0 + nt * 16 + l15;
        float bb = bo[n];
#pragma unroll
        for (int mt = 0; mt < 2; mt++) {
#pragma unroll
            for (int r = 0; r < 4; r++) {
                int m = m0 + wr + mt * 16 + l4 * 4 + r;
                Out[(long)m * D_ + n] = acc[mt][nt][r] + bb;
            }
        }
    }
}

// ------------------------------------------------------------ flash attention
// v0 structure (structural floor per R1-R5): one block = (b,h) x 256-query
// tile; 4 waves x 64 queries. Grid: x = bh (128), y = qt (4).
// S^T = K*Q^T; fixed-max softmax P = exp2 (scale*log2e folded into Q).
// Q pad (d>=48) zeroed IN-REGISTER. l via ones-column at V^T row d=48.
__global__ __launch_bounds__(256) void attn_kernel(
    const unsigned short* __restrict__ Qg, const unsigned short* __restrict__ Kg,
    const unsigned short* __restrict__ Vtg, unsigned short* __restrict__ Ctx) {
    __shared__ __align__(16) unsigned short Ks[64 * 64];    // [key][d] swizzled
    __shared__ __align__(16) unsigned short Vs[64 * 64];    // [d][key] swizzled
    __shared__ __align__(16) unsigned short Ps[4][64 * 64]; // per-wave [q][key] swizzled
    const int tid = threadIdx.x, lane = tid & 63, w = tid >> 6;
    const int l15 = lane & 15, l4 = lane >> 4;
    const int bh = blockIdx.x, qt = blockIdx.y;
    const long qkbase = (long)bh * S_ * PDP;   // Q/K: [bh][s][64]
    const long vbase  = (long)bh * PDP * S_;   // Vt:  [bh][d][1024]

    // Q B-fragments from global; wave w owns queries w*64..w*64+63
    short8 bq[4][2];
#pragma unroll
    for (int g = 0; g < 4; g++) {
        int qrow = qt * 256 + w * 64 + g * 16 + l15;
        bq[g][0] = *(const short8*)&Qg[qkbase + (long)qrow * PDP + l4 * 8];
        bq[g][1] = *(const short8*)&Qg[qkbase + (long)qrow * PDP + 32 + l4 * 8];
    }
    if (l4 >= 2) {   // zero Q pad d=48..63 (chunk1 lanes l4=2,3 hold k=48..63)
        const short8 z8 = {0, 0, 0, 0, 0, 0, 0, 0};
#pragma unroll
        for (int g = 0; g < 4; g++) bq[g][1] = z8;
    }

    const floatx4 zero = {0.f, 0.f, 0.f, 0.f};
    floatx4 accO[4][4];
#pragma unroll
    for (int g = 0; g < 4; g++)
#pragma unroll
        for (int nt = 0; nt < 4; nt++) accO[g][nt] = zero;

    unsigned short* Pw = &Ps[w][0];

    for (int kt = 0; kt < 16; kt++) {
        __syncthreads();
        // stage K [key][d] and V^T [d][key] tiles: 8KB each, direct-to-LDS
#pragma unroll
        for (int i = 0; i < 2; i++) {
            int c = tid + i * 256;
            int row = c >> 3, seg = (c & 7) ^ (row & 7);
            async_copy16(&Kg[qkbase + (long)(kt * 64 + row) * PDP + seg * 8], &Ks[c * 8]);
            async_copy16(&Vtg[vbase + (long)row * S_ + kt * 64 + seg * 8], &Vs[c * 8]);
        }
        __syncthreads();

        // K A-frags, shared across all 4 query groups
        short8 ak[4][2];
#pragma unroll
        for (int ks = 0; ks < 4; ks++) {
            int kr = ks * 16 + l15;
            ak[ks][0] = *(const short8*)&Ks[kr * 64 + ((l4 ^ (kr & 7)) * 8)];
            ak[ks][1] = *(const short8*)&Ks[kr * 64 + (((4 + l4) ^ (kr & 7)) * 8)];
        }

        // scores + P for all groups
#pragma unroll
        for (int g = 0; g < 4; g++) {
            floatx4 sc[4];
#pragma unroll
            for (int ks = 0; ks < 4; ks++) {
                floatx4 a = zero;
                a = __builtin_amdgcn_mfma_f32_16x16x32_bf16(ak[ks][0], bq[g][0], a, 0, 0, 0);
                a = __builtin_amdgcn_mfma_f32_16x16x32_bf16(ak[ks][1], bq[g][1], a, 0, 0, 0);
                sc[ks] = a;
            }
            int prow = g * 16 + l15;
#pragma unroll
            for (int ks = 0; ks < 4; ks++) {
                unsigned short p4[4];
#pragma unroll
                for (int r = 0; r < 4; r++) p4[r] = f2bf(__builtin_amdgcn_exp2f(sc[ks][r]));
                int addr = prow * 64 + (((ks * 2 + (l4 >> 1)) ^ (prow & 7)) * 8) + (l4 & 1) * 4;
                *(uint2*)&Pw[addr] = *(uint2*)&p4[0];
            }
        }

        // PV: V B-frags hoisted per kk, shared across groups
#pragma unroll
        for (int kk = 0; kk < 2; kk++) {
            short8 bv[4];
#pragma unroll
            for (int nt = 0; nt < 4; nt++) {
                int vr = nt * 16 + l15;
                bv[nt] = *(const short8*)&Vs[vr * 64 + (((kk * 4 + l4) ^ (vr & 7)) * 8)];
            }
#pragma unroll
            for (int g = 0; g < 4; g++) {
                int prow = g * 16 + l15;
                short8 ap = *(const short8*)&Pw[prow * 64 + (((kk * 4 + l4) ^ (prow & 7)) * 8)];
#pragma unroll
                for (int nt = 0; nt < 4; nt++)
                    accO[g][nt] = __builtin_amdgcn_mfma_f32_16x16x32_bf16(ap, bv[nt], accO[g][nt], 0, 0, 0);
            }
        }
    }

    // epilogue: l = accO[g][3] at l15==0 (d=48 ones-column); out = accO/l
    const int b = bh >> 4, h = bh & 15;
#pragma unroll
    for (int g = 0; g < 4; g++) {
#pragma unroll
        for (int r = 0; r < 4; r++) {
            float lsum = __shfl(accO[g][3][r], lane & 48);
            float inv = 1.0f / lsum;
            int q = qt * 256 + w * 64 + g * 16 + l4 * 4 + r;
            long rowoff = (long)(b * S_ + q) * D_ + h * PD_;
#pragma unroll
            for (int nt = 0; nt < 3; nt++)
                Ctx[rowoff + nt * 16 + l15] = f2bf(accO[g][nt][r] * inv);
        }
    }
}

// ---------------------------------------------------------------------------
extern "C" void kernel_launch(void* const* d_in, const int* in_sizes, int n_in,
                              void* d_out, int out_size, void* d_ws, size_t ws_size,
                              hipStream_t stream) {
    const float* X  = (const float*)d_in[0];
    const float* Wq = (const float*)d_in[1];
    const float* bq = (const float*)d_in[2];
    const float* Wk = (const float*)d_in[3];
    const float* bk = (const float*)d_in[4];
    const float* Wv = (const float*)d_in[5];
    const float* bv = (const float*)d_in[6];
    const float* Wo = (const float*)d_in[7];
    const float* bo = (const float*)d_in[8];

    unsigned char* ws = (unsigned char*)d_ws;
    const long XB_BYTES  = (long)M_ * D_ * 2;         // 12,582,912
    const long WT_BYTES  = (long)D_ * D_ * 2;         // 1,179,648
    const long QKV_BYTES = (long)BH_ * S_ * PDP * 2;  // 16,777,216

    unsigned short* Xbf   = (unsigned short*)(ws);
    unsigned short* Wtall = (unsigned short*)(ws + XB_BYTES);
    unsigned short* Qws   = (unsigned short*)(ws + XB_BYTES + 4 * WT_BYTES);
    unsigned short* Kws   = Qws + QKV_BYTES / 2;
    unsigned short* Vws   = Kws + QKV_BYTES / 2;
    unsigned short* Vtws  = Vws + QKV_BYTES / 2;
    unsigned short* Ctx   = Vws;  // aliases V (dead after transpose_v)

    prep_kernel<<<8448, 256, 0, stream>>>(X, Xbf, Wq, Wk, Wv, Wo, Wtall);
    gemm_qkv_kernel<<<dim3(64, 4, 3), 256, 0, stream>>>(Xbf, Wtall, bq, bk, bv, Qws);
    transpose_v_kernel<<<dim3(16, 128), 256, 0, stream>>>(Vws, Vtws);
    attn_kernel<<<dim3(128, 4), 256, 0, stream>>>(Qws, Kws, Vtws, Ctx);
    gemm_out_kernel<<<dim3(64, 12), 256, 0, stream>>>(
        Ctx, Wtall + 3 * (WT_BYTES / 2), bo, (float*)d_out);
}

// Round 12
// 191.018 us; speedup vs baseline: 1.0223x; 1.0223x over previous
//
#include <hip/hip_runtime.h>
#include <hip/hip_bf16.h>

// Problem constants
#define B_   8
#define S_   1024
#define D_   768
#define H_   16
#define PD_  48
#define PDP  64        // padded per-head dim
#define M_   8192      // B*S
#define BH_  128       // B*H

// 1/sqrt(48) * log2(e)  -> folded into Q so softmax is a bare exp2
#define QSCALE 0.20823031f

typedef __attribute__((ext_vector_type(8))) short short8;
typedef __attribute__((ext_vector_type(4))) float floatx4;

__device__ __forceinline__ unsigned short f2bf(float f) {
    __hip_bfloat16 h = __float2bfloat16(f);
    return *reinterpret_cast<unsigned short*>(&h);
}

// async 16B global -> LDS (direct, no VGPR round trip). LDS dest must be
// wave-uniform base + lane*16; any swizzle must be folded into the GLOBAL addr.
__device__ __forceinline__ void async_copy16(const unsigned short* gptr, unsigned short* lptr) {
    __builtin_amdgcn_global_load_lds(
        (const __attribute__((address_space(1))) unsigned int*)gptr,
        (__attribute__((address_space(3))) unsigned int*)lptr, 16, 0, 0);
}

// ---------------------------------------- fused: convert X + transpose weights
// blocks [0,6144): cast X tile to bf16. blocks [6144,8448): W transpose+cast.
__global__ __launch_bounds__(256) void prep_kernel(
    const float* __restrict__ X, unsigned short* __restrict__ Xb,
    const float* __restrict__ w0, const float* __restrict__ w1,
    const float* __restrict__ w2, const float* __restrict__ w3,
    unsigned short* __restrict__ Wtall) {
    __shared__ float tile[32][33];
    const int tid = threadIdx.x;
    const int bx = blockIdx.x;
    if (bx < 6144) {
        long i = ((long)bx * 256 + tid) * 4;
        float4 v = *(const float4*)(X + i);
        ushort4 o;
        o.x = f2bf(v.x); o.y = f2bf(v.y); o.z = f2bf(v.z); o.w = f2bf(v.w);
        *(ushort4*)(Xb + i) = o;
        return;
    }
    const int t = bx - 6144;
    const int z = t / 576, r = t % 576;
    const int nt = (r % 24) * 32, kt = (r / 24) * 32;
    const int tx = tid & 31, ty = tid >> 5;
    const float* W = (z == 0) ? w0 : (z == 1) ? w1 : (z == 2) ? w2 : w3;
    unsigned short* Wt = Wtall + (long)z * D_ * D_;
#pragma unroll
    for (int i = 0; i < 4; i++)
        tile[ty + i * 8][tx] = W[(long)(kt + ty + i * 8) * D_ + nt + tx];
    __syncthreads();
#pragma unroll
    for (int i = 0; i < 4; i++)
        Wt[(long)(nt + ty + i * 8) * D_ + kt + tx] = f2bf(tile[tx][ty + i * 8]);
}

// ------------------------------------------------------- QKV projection GEMM
// BN=192 (4 heads exactly) — R10-verified win. Stall-bound at per-k-step
// barrier drains; wide B-tile buys 48 MFMA/wave per barrier pair; same MFMA
// issue per CU-interval but 1/3 fewer chip-wide drain events + A re-stages.
// Grid 64 x 4 x 3 = 768 blocks = exactly 3.0 blocks/CU.
// LDS = 16KB(A) + 24KB(B) = 40KB. __launch_bounds__(256,3) caps VGPR at 170.
// m-major grid x => per-XCD L2 pins 8 A-tiles; one B-tile streams at a time.
// (R11 lesson: widen the OUTPUT tile to amortize barriers, not the K depth —
// BK=128 in gemm_out regressed.)
__global__ __launch_bounds__(256, 3) void gemm_qkv_kernel(
    const unsigned short* __restrict__ Xb, const unsigned short* __restrict__ Wtall,
    const float* __restrict__ bq, const float* __restrict__ bk,
    const float* __restrict__ bv, unsigned short* __restrict__ QKV) {
    __shared__ __align__(16) unsigned short Asm[128 * 64];
    __shared__ __align__(16) unsigned short Bsm[192 * 64];
    const int z = blockIdx.z;
    const int m0 = blockIdx.x * 128, n0 = blockIdx.y * 192;
    const float* bias = (z == 0) ? bq : (z == 1) ? bk : bv;
    const float vscale = (z == 0) ? QSCALE : 1.0f;
    const unsigned short* Ag  = Xb + (long)m0 * D_;
    const unsigned short* Btg = Wtall + (long)z * D_ * D_ + (long)n0 * D_;

    const int tid = threadIdx.x, lane = tid & 63, w = tid >> 6;
    const int wr = (w >> 1) * 64, wc = (w & 1) * 96;
    const int l15 = lane & 15, l4 = lane >> 4;
    const floatx4 zero = {0.f, 0.f, 0.f, 0.f};
    floatx4 acc[4][6];
#pragma unroll
    for (int mt = 0; mt < 4; mt++)
#pragma unroll
        for (int nt = 0; nt < 6; nt++) acc[mt][nt] = zero;

    for (int kb = 0; kb < D_; kb += 64) {
        // stage A[128x64]: 1024 16B chunks; B[192x64]: 1536 chunks.
#pragma unroll
        for (int i = 0; i < 4; i++) {
            int c = tid + i * 256;
            int row = c >> 3, seg = (c & 7) ^ (row & 7);
            async_copy16(&Ag[(long)row * D_ + kb + seg * 8], &Asm[c * 8]);
        }
#pragma unroll
        for (int i = 0; i < 6; i++) {
            int c = tid + i * 256;
            int row = c >> 3, seg = (c & 7) ^ (row & 7);
            async_copy16(&Btg[(long)row * D_ + kb + seg * 8], &Bsm[c * 8]);
        }
        __syncthreads();
#pragma unroll
        for (int kk = 0; kk < 2; kk++) {
            short8 af[4], bf[6];
#pragma unroll
            for (int mt = 0; mt < 4; mt++) {
                int r = wr + mt * 16 + l15;
                af[mt] = *(const short8*)&Asm[r * 64 + (((kk * 4 + l4) ^ (r & 7)) * 8)];
            }
#pragma unroll
            for (int nt = 0; nt < 6; nt++) {
                int c = wc + nt * 16 + l15;
                bf[nt] = *(const short8*)&Bsm[c * 64 + (((kk * 4 + l4) ^ (c & 7)) * 8)];
            }
#pragma unroll
            for (int mt = 0; mt < 4; mt++)
#pragma unroll
                for (int nt = 0; nt < 6; nt++)
                    acc[mt][nt] = __builtin_amdgcn_mfma_f32_16x16x32_bf16(
                        af[mt], bf[nt], acc[mt][nt], 0, 0, 0);
        }
        __syncthreads();
    }

    unsigned short* out = QKV + (long)z * BH_ * S_ * PDP;
#pragma unroll
    for (int nt = 0; nt < 6; nt++) {
        int n = n0 + wc + nt * 16 + l15;
        int h = n / PD_, pd = n % PD_;
        float bb = bias[n];
#pragma unroll
        for (int mt = 0; mt < 4; mt++) {
#pragma unroll
            for (int r = 0; r < 4; r++) {
                int m = m0 + wr + mt * 16 + l4 * 4 + r;
                int b = m >> 10, s = m & 1023;
                out[((long)(b * H_ + h) * S_ + s) * PDP + pd] = f2bf((acc[mt][nt][r] + bb) * vscale);
            }
        }
    }
}

// --------------------------------------------- V transpose: [bh,s,64]->[bh,64,s]
// Also writes the l-accumulator ones-column at d=48 and zeros at d=49..63.
__global__ __launch_bounds__(256) void transpose_v_kernel(
    const unsigned short* __restrict__ V, unsigned short* __restrict__ Vt) {
    __shared__ __align__(16) unsigned short T[64 * 64];  // [s][d] swizzled
    const int tid = threadIdx.x;
    const int st = blockIdx.x * 64, bh = blockIdx.y;
    const unsigned short* src = V + (long)bh * S_ * PDP;
    unsigned short* dst = Vt + (long)bh * PDP * S_;
#pragma unroll
    for (int i = 0; i < 2; i++) {
        int c = tid + i * 256;
        int row = c >> 3, seg = (c & 7) ^ (row & 7);
        async_copy16(&src[(long)(st + row) * PDP + seg * 8], &T[c * 8]);
    }
    __syncthreads();
    const int d = tid >> 2;
    unsigned short tmp[16];
#pragma unroll
    for (int j = 0; j < 16; j++) {
        int sl = (tid & 3) * 16 + j;
        unsigned short v = T[sl * 64 + ((d >> 3) ^ (sl & 7)) * 8 + (d & 7)];
        tmp[j] = (d < PD_) ? v : ((d == PD_) ? (unsigned short)0x3F80 : (unsigned short)0);
    }
    *(uint4*)&dst[(long)d * S_ + st + (tid & 3) * 16] = *(uint4*)&tmp[0];
    *(uint4*)&dst[(long)d * S_ + st + (tid & 3) * 16 + 8] = *(uint4*)&tmp[8];
}

// --------------------------------------------------------- output projection
// BN=64 tiles: grid 64x12 = 768 blocks = 3.0/CU (1.5/CU quantization fixed in
// R6; BK=128 variant falsified in R11 — BK=64 is the verified best).
// 4 waves x (32 rows x 64 cols), acc[2][4].
__global__ __launch_bounds__(256) void gemm_out_kernel(
    const unsigned short* __restrict__ Ctx, const unsigned short* __restrict__ Wot,
    const float* __restrict__ bo, float* __restrict__ Out) {
    __shared__ __align__(16) unsigned short Asm[128 * 64];
    __shared__ __align__(16) unsigned short Bsm[64 * 64];
    const int tid = threadIdx.x, lane = tid & 63, w = tid >> 6;
    const int wr = w * 32;
    const int l15 = lane & 15, l4 = lane >> 4;
    const int m0 = blockIdx.x * 128, n0 = blockIdx.y * 64;
    const unsigned short* Ag = Ctx + (long)m0 * D_;
    const unsigned short* Btg = Wot + (long)n0 * D_;

    const floatx4 zero = {0.f, 0.f, 0.f, 0.f};
    floatx4 acc[2][4];
#pragma unroll
    for (int mt = 0; mt < 2; mt++)
#pragma unroll
        for (int nt = 0; nt < 4; nt++) acc[mt][nt] = zero;

    for (int kb = 0; kb < D_; kb += 64) {
#pragma unroll
        for (int i = 0; i < 4; i++) {
            int c = tid + i * 256;
            int row = c >> 3, seg = (c & 7) ^ (row & 7);
            async_copy16(&Ag[(long)row * D_ + kb + seg * 8], &Asm[c * 8]);
        }
#pragma unroll
        for (int i = 0; i < 2; i++) {
            int c = tid + i * 256;
            int row = c >> 3, seg = (c & 7) ^ (row & 7);
            async_copy16(&Btg[(long)row * D_ + kb + seg * 8], &Bsm[c * 8]);
        }
        __syncthreads();
#pragma unroll
        for (int kk = 0; kk < 2; kk++) {
            short8 af[2], bf[4];
#pragma unroll
            for (int mt = 0; mt < 2; mt++) {
                int r = wr + mt * 16 + l15;
                af[mt] = *(const short8*)&Asm[r * 64 + (((kk * 4 + l4) ^ (r & 7)) * 8)];
            }
#pragma unroll
            for (int nt = 0; nt < 4; nt++) {
                int c = nt * 16 + l15;
                bf[nt] = *(const short8*)&Bsm[c * 64 + (((kk * 4 + l4) ^ (c & 7)) * 8)];
            }
#pragma unroll
            for (int mt = 0; mt < 2; mt++)
#pragma unroll
                for (int nt = 0; nt < 4; nt++)
                    acc[mt][nt] = __builtin_amdgcn_mfma_f32_16x16x32_bf16(
                        af[mt], bf[nt], acc[mt][nt], 0, 0, 0);
        }
        __syncthreads();
    }

#pragma unroll
    for (int nt = 0; nt < 4; nt++) {
        int n = n0 + nt * 16 + l15;
        float bb = bo[n];
#pragma unroll
        for (int mt = 0; mt < 2; mt++) {
#pragma unroll
            for (int r = 0; r < 4; r++) {
                int m = m0 + wr + mt * 16 + l4 * 4 + r;
                Out[(long)m * D_ + n] = acc[mt][nt][r] + bb;
            }
        }
    }
}

// ------------------------------------------------------------ flash attention
// v0 structure (structural floor per R1-R5): one block = (b,h) x 256-query
// tile; 4 waves x 64 queries. Grid: x = bh (128), y = qt (4).
// S^T = K*Q^T; fixed-max softmax P = exp2 (scale*log2e folded into Q).
// Q pad (d>=48) zeroed IN-REGISTER. l via ones-column at V^T row d=48.
__global__ __launch_bounds__(256) void attn_kernel(
    const unsigned short* __restrict__ Qg, const unsigned short* __restrict__ Kg,
    const unsigned short* __restrict__ Vtg, unsigned short* __restrict__ Ctx) {
    __shared__ __align__(16) unsigned short Ks[64 * 64];    // [key][d] swizzled
    __shared__ __align__(16) unsigned short Vs[64 * 64];    // [d][key] swizzled
    __shared__ __align__(16) unsigned short Ps[4][64 * 64]; // per-wave [q][key] swizzled
    const int tid = threadIdx.x, lane = tid & 63, w = tid >> 6;
    const int l15 = lane & 15, l4 = lane >> 4;
    const int bh = blockIdx.x, qt = blockIdx.y;
    const long qkbase = (long)bh * S_ * PDP;   // Q/K: [bh][s][64]
    const long vbase  = (long)bh * PDP * S_;   // Vt:  [bh][d][1024]

    // Q B-fragments from global; wave w owns queries w*64..w*64+63
    short8 bq[4][2];
#pragma unroll
    for (int g = 0; g < 4; g++) {
        int qrow = qt * 256 + w * 64 + g * 16 + l15;
        bq[g][0] = *(const short8*)&Qg[qkbase + (long)qrow * PDP + l4 * 8];
        bq[g][1] = *(const short8*)&Qg[qkbase + (long)qrow * PDP + 32 + l4 * 8];
    }
    if (l4 >= 2) {   // zero Q pad d=48..63 (chunk1 lanes l4=2,3 hold k=48..63)
        const short8 z8 = {0, 0, 0, 0, 0, 0, 0, 0};
#pragma unroll
        for (int g = 0; g < 4; g++) bq[g][1] = z8;
    }

    const floatx4 zero = {0.f, 0.f, 0.f, 0.f};
    floatx4 accO[4][4];
#pragma unroll
    for (int g = 0; g < 4; g++)
#pragma unroll
        for (int nt = 0; nt < 4; nt++) accO[g][nt] = zero;

    unsigned short* Pw = &Ps[w][0];

    for (int kt = 0; kt < 16; kt++) {
        __syncthreads();
        // stage K [key][d] and V^T [d][key] tiles: 8KB each, direct-to-LDS
#pragma unroll
        for (int i = 0; i < 2; i++) {
            int c = tid + i * 256;
            int row = c >> 3, seg = (c & 7) ^ (row & 7);
            async_copy16(&Kg[qkbase + (long)(kt * 64 + row) * PDP + seg * 8], &Ks[c * 8]);
            async_copy16(&Vtg[vbase + (long)row * S_ + kt * 64 + seg * 8], &Vs[c * 8]);
        }
        __syncthreads();

        // K A-frags, shared across all 4 query groups
        short8 ak[4][2];
#pragma unroll
        for (int ks = 0; ks < 4; ks++) {
            int kr = ks * 16 + l15;
            ak[ks][0] = *(const short8*)&Ks[kr * 64 + ((l4 ^ (kr & 7)) * 8)];
            ak[ks][1] = *(const short8*)&Ks[kr * 64 + (((4 + l4) ^ (kr & 7)) * 8)];
        }

        // scores + P for all groups
#pragma unroll
        for (int g = 0; g < 4; g++) {
            floatx4 sc[4];
#pragma unroll
            for (int ks = 0; ks < 4; ks++) {
                floatx4 a = zero;
                a = __builtin_amdgcn_mfma_f32_16x16x32_bf16(ak[ks][0], bq[g][0], a, 0, 0, 0);
                a = __builtin_amdgcn_mfma_f32_16x16x32_bf16(ak[ks][1], bq[g][1], a, 0, 0, 0);
                sc[ks] = a;
            }
            int prow = g * 16 + l15;
#pragma unroll
            for (int ks = 0; ks < 4; ks++) {
                unsigned short p4[4];
#pragma unroll
                for (int r = 0; r < 4; r++) p4[r] = f2bf(__builtin_amdgcn_exp2f(sc[ks][r]));
                int addr = prow * 64 + (((ks * 2 + (l4 >> 1)) ^ (prow & 7)) * 8) + (l4 & 1) * 4;
                *(uint2*)&Pw[addr] = *(uint2*)&p4[0];
            }
        }

        // PV: V B-frags hoisted per kk, shared across groups
#pragma unroll
        for (int kk = 0; kk < 2; kk++) {
            short8 bv[4];
#pragma unroll
            for (int nt = 0; nt < 4; nt++) {
                int vr = nt * 16 + l15;
                bv[nt] = *(const short8*)&Vs[vr * 64 + (((kk * 4 + l4) ^ (vr & 7)) * 8)];
            }
#pragma unroll
            for (int g = 0; g < 4; g++) {
                int prow = g * 16 + l15;
                short8 ap = *(const short8*)&Pw[prow * 64 + (((kk * 4 + l4) ^ (prow & 7)) * 8)];
#pragma unroll
                for (int nt = 0; nt < 4; nt++)
                    accO[g][nt] = __builtin_amdgcn_mfma_f32_16x16x32_bf16(ap, bv[nt], accO[g][nt], 0, 0, 0);
            }
        }
    }

    // epilogue: l = accO[g][3] at l15==0 (d=48 ones-column); out = accO/l
    const int b = bh >> 4, h = bh & 15;
#pragma unroll
    for (int g = 0; g < 4; g++) {
#pragma unroll
        for (int r = 0; r < 4; r++) {
            float lsum = __shfl(accO[g][3][r], lane & 48);
            float inv = 1.0f / lsum;
            int q = qt * 256 + w * 64 + g * 16 + l4 * 4 + r;
            long rowoff = (long)(b * S_ + q) * D_ + h * PD_;
#pragma unroll
            for (int nt = 0; nt < 3; nt++)
                Ctx[rowoff + nt * 16 + l15] = f2bf(accO[g][nt][r] * inv);
        }
    }
}

// ---------------------------------------------------------------------------
extern "C" void kernel_launch(void* const* d_in, const int* in_sizes, int n_in,
                              void* d_out, int out_size, void* d_ws, size_t ws_size,
                              hipStream_t stream) {
    const float* X  = (const float*)d_in[0];
    const float* Wq = (const float*)d_in[1];
    const float* bq = (const float*)d_in[2];
    const float* Wk = (const float*)d_in[3];
    const float* bk = (const float*)d_in[4];
    const float* Wv = (const float*)d_in[5];
    const float* bv = (const float*)d_in[6];
    const float* Wo = (const float*)d_in[7];
    const float* bo = (const float*)d_in[8];

    unsigned char* ws = (unsigned char*)d_ws;
    const long XB_BYTES  = (long)M_ * D_ * 2;         // 12,582,912
    const long WT_BYTES  = (long)D_ * D_ * 2;         // 1,179,648
    const long QKV_BYTES = (long)BH_ * S_ * PDP * 2;  // 16,777,216

    unsigned short* Xbf   = (unsigned short*)(ws);
    unsigned short* Wtall = (unsigned short*)(ws + XB_BYTES);
    unsigned short* Qws   = (unsigned short*)(ws + XB_BYTES + 4 * WT_BYTES);
    unsigned short* Kws   = Qws + QKV_BYTES / 2;
    unsigned short* Vws   = Kws + QKV_BYTES / 2;
    unsigned short* Vtws  = Vws + QKV_BYTES / 2;
    unsigned short* Ctx   = Vws;  // aliases V (dead after transpose_v)

    prep_kernel<<<8448, 256, 0, stream>>>(X, Xbf, Wq, Wk, Wv, Wo, Wtall);
    gemm_qkv_kernel<<<dim3(64, 4, 3), 256, 0, stream>>>(Xbf, Wtall, bq, bk, bv, Qws);
    transpose_v_kernel<<<dim3(16, 128), 256, 0, stream>>>(Vws, Vtws);
    attn_kernel<<<dim3(128, 4), 256, 0, stream>>>(Qws, Kws, Vtws, Ctx);
    gemm_out_kernel<<<dim3(64, 12), 256, 0, stream>>>(
        Ctx, Wtall + 3 * (WT_BYTES / 2), bo, (float*)d_out);
}